// Round 7
// baseline (211.851 us; speedup 1.0000x reference)
//
#include <hip/hip_runtime.h>
#include <math.h>

// BandpassFilter: out = lowpass_biquad(x) - highpass_biquad(x), f32,
// shape (32,2,220500). Exact chunked-scan parallelization of the order-2 IIR.
//
// R9: wave-autonomous phases on the PROVEN co-resident lookback skeleton.
// R8 (wave tiles + 2 blocks/CU + atomic-ticket ordering) hung the container
// twice; the ticket scheme without co-residency was the unproven mechanism.
// R9 keeps the convoy fix but restores the R5-R7 structure wholesale:
//  - blockIdx-based decoupled lookback, 896 blocks CO-RESIDENT at 4
//    blocks/CU (proven across R5/R6/R7 + R4's cooperative-launch capacity
//    proof). No tickets.
//  - wave-private HALF-tiles [64][33] (8.4 KB/wave, 33.8 KB/block): phase A
//    is stage->wave-local lgkmcnt fence->compute, all 64 lanes busy, ZERO
//    block barriers in the heavy phases. Staging is coalesced at 128-B-line
//    granularity (8 lanes cover exactly one line).
//  - phase C needs no LDS: each lane's chunk is one aligned 256-B line,
//    L2/L3-hot from phase A; 16x {load f4, 4 samples, store f4}; stores
//    write full lines per lane -> no write amplification.
// R7 post-mortem stands: bottleneck is the block-wide barrier convoy
// (VALUBusy 12.6%, HBM 18%, kernel 85us vs ~27us overlapped floor).

namespace {

constexpr int T_LEN  = 220500;
constexpr int NCH    = 64;                          // 32 batch * 2 channels
constexpr int CHUNK  = 64;                          // samples per chunk
constexpr int NCHUNK = (T_LEN + CHUNK - 1) / CHUNK; // 3446 (last chunk = 20)
constexpr int CPB    = 256;                         // chunks per block
constexpr int BX     = (NCHUNK + CPB - 1) / CPB;    // 14 blocks along chunk dim
constexpr int NBLK   = BX * NCH;                    // 896 blocks
constexpr int HSTR   = 33;                          // 32+1: half-tile row stride
constexpr int WROW   = CHUNK * HSTR;                // 2112 floats per wave tile

struct Coeffs { float b0, b1, b2, a1, a2; };

__device__ inline Coeffs make_coeffs(float sr, float cutoff, bool hp) {
    float w0 = 6.2831853071795864f * cutoff / sr;
    float c = cosf(w0), s = sinf(w0);
    float alpha = s / (2.0f * 0.707f);
    float b0, b1;
    if (!hp) { b0 = (1.0f - c) * 0.5f; b1 = 1.0f - c; }
    else     { b0 = (1.0f + c) * 0.5f; b1 = -(1.0f + c); }
    float inv = 1.0f / (1.0f + alpha);
    Coeffs k;
    k.b0 = b0 * inv; k.b1 = b1 * inv; k.b2 = b0 * inv;
    k.a1 = (-2.0f * c) * inv;
    k.a2 = (1.0f - alpha) * inv;
    return k;
}

// one sample through both filters; returns yl - yh
__device__ inline float proc_sample(float xn, float& x1, float& x2,
                                    const Coeffs& lo, const Coeffs& hi,
                                    float& yl1, float& yl2,
                                    float& yh1, float& yh2) {
    float ffl = fmaf(lo.b0, xn, fmaf(lo.b1, x1, lo.b2 * x2));
    float tl  = fmaf(-lo.a2, yl2, ffl);
    float yl  = fmaf(-lo.a1, yl1, tl);
    float ffh = fmaf(hi.b0, xn, fmaf(hi.b1, x1, hi.b2 * x2));
    float th  = fmaf(-hi.a2, yh2, ffh);
    float yh  = fmaf(-hi.a1, yh1, th);
    yl2 = yl1; yl1 = yl;
    yh2 = yh1; yh1 = yh;
    x2 = x1; x1 = xn;
    return yl - yh;
}

// Affine map s' = A*s + c on the 2-tap IIR state s = (y[n-1], y[n-2]).
struct Aff { float a00, a01, a10, a11, c0, c1; };

__device__ inline Aff aff_id() { return {1.f, 0.f, 0.f, 1.f, 0.f, 0.f}; }

// g o f : f applied first. Same formulas as the R2/R5-verified scan.
__device__ inline Aff aff_compose(const Aff& g, const Aff& f) {
    Aff r;
    r.a00 = fmaf(g.a00, f.a00, g.a01 * f.a10);
    r.a01 = fmaf(g.a00, f.a01, g.a01 * f.a11);
    r.a10 = fmaf(g.a10, f.a00, g.a11 * f.a10);
    r.a11 = fmaf(g.a10, f.a01, g.a11 * f.a11);
    r.c0  = fmaf(g.a00, f.c0, fmaf(g.a01, f.c1, g.c0));
    r.c1  = fmaf(g.a10, f.c0, fmaf(g.a11, f.c1, g.c1));
    return r;
}

__device__ inline Aff aff_shfl_up(const Aff& e, int d) {
    Aff p;
    p.a00 = __shfl_up(e.a00, d);
    p.a01 = __shfl_up(e.a01, d);
    p.a10 = __shfl_up(e.a10, d);
    p.a11 = __shfl_up(e.a11, d);
    p.c0  = __shfl_up(e.c0, d);
    p.c1  = __shfl_up(e.c1, d);
    return p;
}

// M^CHUNK for one filter: chunk transition matrix, CHUNK=64 via 6 squarings.
__device__ inline void chunk_matrix(const Coeffs& k,
                                    float& m00, float& m01,
                                    float& m10, float& m11) {
    m00 = -k.a1; m01 = -k.a2; m10 = 1.0f; m11 = 0.0f;
    #pragma unroll
    for (int i = 0; i < 6; ++i) {
        float t00 = fmaf(m00, m00, m01 * m10);
        float t01 = fmaf(m00, m01, m01 * m11);
        float t10 = fmaf(m10, m00, m11 * m10);
        float t11 = fmaf(m10, m01, m11 * m11);
        m00 = t00; m01 = t01; m10 = t10; m11 = t11;
    }
}

__global__ __launch_bounds__(256)
__attribute__((amdgpu_waves_per_eu(4, 4)))   // pin 4 waves/EU: VGPR<=128,
void k_bandpass(const float* __restrict__ x, // no 8-wave spill chase (R6)
                const int* __restrict__ srp,
                const float* __restrict__ clp,
                const float* __restrict__ chp,
                float* __restrict__ agg,          // [NBLK][12] aggregates
                unsigned int* __restrict__ flags, // [NBLK] 0=empty 1=ready
                float* __restrict__ out) {
    __shared__ float tile[4 * WROW];           // 33,792 B: 4 wave half-tiles
    __shared__ Aff ldsWaveL[4], ldsWaveH[4];   // wave inclusive totals
    __shared__ Aff ldsWL[4],  ldsWH[4];        // wave exclusive prefixes
    __shared__ Aff ldsLBl[BX], ldsLBh[BX];     // lookback payloads
    __shared__ float ldsCB[4];                 // block entry state (lo, hi)
    // total LDS ~34.9 KB -> 4 blocks/CU -> 1024 resident slots >= 896 (proven)

    const int t    = threadIdx.x;
    const int w    = t >> 6;
    const int lane = t & 63;
    const int ch   = blockIdx.y;
    const int bx   = blockIdx.x;
    const int pb   = bx * CPB;
    const int bid  = ch * BX + bx;

    float sr = (float)(*srp);
    Coeffs lo = make_coeffs(sr, *clp, false);
    Coeffs hi = make_coeffs(sr, *chp, true);

    const float* __restrict__ xc = x + (size_t)ch * T_LEN;
    const int wc0 = pb + w * CHUNK;            // first chunk of this wave
    const int p   = wc0 + lane;                // this lane's chunk
    const bool active = (p < NCHUNK);
    const int s   = p * CHUNK;                 // lane chunk = one 256-B line
    const int wbF = wc0 * CHUNK;               // wave region base (floats)

    float* __restrict__ tw = &tile[w * WROW];  // wave-private half-tile

    // x history (exact; crosses chunk/wave/block boundaries by global read)
    float x1 = (active && s >= 1) ? xc[s - 1] : 0.0f;
    float x2 = (active && s >= 2) ? xc[s - 2] : 0.0f;

    // stage half h of the wave's 64 chunks: 8 lanes cover exactly one
    // 128-B line -> fully coalesced; OOB zero-filled (only the last chunk's
    // never-consumed tail region).
    auto stageHalf = [&](int h) {
        #pragma unroll
        for (int i = 0; i < 8; ++i) {
            int f4 = i * 64 + lane;
            int c  = f4 >> 3;              // local chunk row 0..63
            int j0 = (f4 & 7) * 4;         // sample within half
            int ga = wbF + c * CHUNK + h * 32 + j0;
            float4 v = make_float4(0.f, 0.f, 0.f, 0.f);
            if (ga < T_LEN) v = *(const float4*)(xc + ga);   // T_LEN%4==0
            float* d = &tw[c * HSTR + j0];
            d[0] = v.x; d[1] = v.y; d[2] = v.z; d[3] = v.w;
        }
    };

    // ---- phase A: zero-state run, all lanes busy, NO block barriers -----
    float tl1 = 0.f, tl2 = 0.f, th1 = 0.f, th2 = 0.f;
    {
        float ax1 = x1, ax2 = x2;
        #pragma unroll
        for (int h = 0; h < 2; ++h) {
            stageHalf(h);
            // wave-internal fence: drain this wave's ds_writes (all 64
            // lanes' data) before cross-lane reads; rule-#18 sched fence.
            asm volatile("s_waitcnt lgkmcnt(0)" ::: "memory");
            __builtin_amdgcn_sched_barrier(0);
            const float* __restrict__ L = &tw[lane * HSTR];
            #pragma unroll
            for (int j = 0; j < 32; ++j)
                (void)proc_sample(L[j], ax1, ax2, lo, hi, tl1, tl2, th1, th2);
        }
    }
    // (last chunk's zero-padded tail junk only affects its own Aff; it is
    //  the globally-last chunk -> never consumed downstream)

    // ---- block-level affine scan over the 256 per-chunk maps (proven) ---
    float Ml00, Ml01, Ml10, Ml11, Mh00, Mh01, Mh10, Mh11;
    chunk_matrix(lo, Ml00, Ml01, Ml10, Ml11);
    chunk_matrix(hi, Mh00, Mh01, Mh10, Mh11);

    Aff il = active ? Aff{Ml00, Ml01, Ml10, Ml11, tl1, tl2} : aff_id();
    Aff ih = active ? Aff{Mh00, Mh01, Mh10, Mh11, th1, th2} : aff_id();

    #pragma unroll
    for (int d = 1; d < 64; d <<= 1) {
        Aff plx = aff_shfl_up(il, d);
        Aff phx = aff_shfl_up(ih, d);
        if (lane >= d) {
            il = aff_compose(il, plx);
            ih = aff_compose(ih, phx);
        }
    }
    if (lane == 63) { ldsWaveL[w] = il; ldsWaveH[w] = ih; }
    __syncthreads();

    if (t == 0) {
        Aff rl = aff_id(), rh = aff_id();
        #pragma unroll
        for (int ww = 0; ww < 4; ++ww) {
            ldsWL[ww] = rl; ldsWH[ww] = rh;
            rl = aff_compose(ldsWaveL[ww], rl);
            rh = aff_compose(ldsWaveH[ww], rh);
        }
        // publish block aggregate (proven R5 protocol: relaxed payload +
        // release flag, agent scope)
        float* pl = agg + (size_t)bid * 12;
        __hip_atomic_store(pl + 0,  rl.a00, __ATOMIC_RELAXED, __HIP_MEMORY_SCOPE_AGENT);
        __hip_atomic_store(pl + 1,  rl.a01, __ATOMIC_RELAXED, __HIP_MEMORY_SCOPE_AGENT);
        __hip_atomic_store(pl + 2,  rl.a10, __ATOMIC_RELAXED, __HIP_MEMORY_SCOPE_AGENT);
        __hip_atomic_store(pl + 3,  rl.a11, __ATOMIC_RELAXED, __HIP_MEMORY_SCOPE_AGENT);
        __hip_atomic_store(pl + 4,  rl.c0,  __ATOMIC_RELAXED, __HIP_MEMORY_SCOPE_AGENT);
        __hip_atomic_store(pl + 5,  rl.c1,  __ATOMIC_RELAXED, __HIP_MEMORY_SCOPE_AGENT);
        __hip_atomic_store(pl + 6,  rh.a00, __ATOMIC_RELAXED, __HIP_MEMORY_SCOPE_AGENT);
        __hip_atomic_store(pl + 7,  rh.a01, __ATOMIC_RELAXED, __HIP_MEMORY_SCOPE_AGENT);
        __hip_atomic_store(pl + 8,  rh.a10, __ATOMIC_RELAXED, __HIP_MEMORY_SCOPE_AGENT);
        __hip_atomic_store(pl + 9,  rh.a11, __ATOMIC_RELAXED, __HIP_MEMORY_SCOPE_AGENT);
        __hip_atomic_store(pl + 10, rh.c0,  __ATOMIC_RELAXED, __HIP_MEMORY_SCOPE_AGENT);
        __hip_atomic_store(pl + 11, rh.c1,  __ATOMIC_RELAXED, __HIP_MEMORY_SCOPE_AGENT);
        __hip_atomic_store(&flags[bid], 1u, __ATOMIC_RELEASE, __HIP_MEMORY_SCOPE_AGENT);
    }
    __syncthreads();

    // per-thread block-exclusive prefix = (wave-exclusive of thread) o W[wave]
    Aff exL, exH;
    {
        Aff pl_ = aff_shfl_up(il, 1);
        Aff ph_ = aff_shfl_up(ih, 1);
        if (lane == 0) { pl_ = aff_id(); ph_ = aff_id(); }
        exL = aff_compose(pl_, ldsWL[w]);
        exH = aff_compose(ph_, ldsWH[w]);
    }

    // ---- lookback: wave 0 polls the <=13 predecessors (proven R5-R7) ----
    if (bx > 0) {
        if (t < bx) {   // lanes 0..bx-1 of wave 0
            int idx = ch * BX + t;
            // cache-neutral spin (proven R6/R7): relaxed SYSTEM loads;
            // hang-proof fallback to acquire-AGENT after 1024 spins.
            int spins = 0;
            for (;;) {
                unsigned int f = (spins < 1024)
                    ? __hip_atomic_load(&flags[idx], __ATOMIC_RELAXED,
                                        __HIP_MEMORY_SCOPE_SYSTEM)
                    : __hip_atomic_load(&flags[idx], __ATOMIC_ACQUIRE,
                                        __HIP_MEMORY_SCOPE_AGENT);
                if (f != 0u) break;
                __builtin_amdgcn_s_sleep(2);
                ++spins;
            }
            // one acquire to order the payload reads (proven R5 semantics)
            (void)__hip_atomic_load(&flags[idx], __ATOMIC_ACQUIRE,
                                    __HIP_MEMORY_SCOPE_AGENT);
            const float* pp = agg + (size_t)idx * 12;
            Aff al, ah;
            al.a00 = __hip_atomic_load(pp + 0,  __ATOMIC_RELAXED, __HIP_MEMORY_SCOPE_AGENT);
            al.a01 = __hip_atomic_load(pp + 1,  __ATOMIC_RELAXED, __HIP_MEMORY_SCOPE_AGENT);
            al.a10 = __hip_atomic_load(pp + 2,  __ATOMIC_RELAXED, __HIP_MEMORY_SCOPE_AGENT);
            al.a11 = __hip_atomic_load(pp + 3,  __ATOMIC_RELAXED, __HIP_MEMORY_SCOPE_AGENT);
            al.c0  = __hip_atomic_load(pp + 4,  __ATOMIC_RELAXED, __HIP_MEMORY_SCOPE_AGENT);
            al.c1  = __hip_atomic_load(pp + 5,  __ATOMIC_RELAXED, __HIP_MEMORY_SCOPE_AGENT);
            ah.a00 = __hip_atomic_load(pp + 6,  __ATOMIC_RELAXED, __HIP_MEMORY_SCOPE_AGENT);
            ah.a01 = __hip_atomic_load(pp + 7,  __ATOMIC_RELAXED, __HIP_MEMORY_SCOPE_AGENT);
            ah.a10 = __hip_atomic_load(pp + 8,  __ATOMIC_RELAXED, __HIP_MEMORY_SCOPE_AGENT);
            ah.a11 = __hip_atomic_load(pp + 9,  __ATOMIC_RELAXED, __HIP_MEMORY_SCOPE_AGENT);
            ah.c0  = __hip_atomic_load(pp + 10, __ATOMIC_RELAXED, __HIP_MEMORY_SCOPE_AGENT);
            ah.c1  = __hip_atomic_load(pp + 11, __ATOMIC_RELAXED, __HIP_MEMORY_SCOPE_AGENT);
            ldsLBl[t] = al; ldsLBh[t] = ah;
        }
        __syncthreads();
        if (t == 0) {
            Aff rl = ldsLBl[0], rh = ldsLBh[0];
            for (int l = 1; l < bx; ++l) {
                rl = aff_compose(ldsLBl[l], rl);
                rh = aff_compose(ldsLBh[l], rh);
            }
            ldsCB[0] = rl.c0; ldsCB[1] = rl.c1;   // entry state = prefix(0)
            ldsCB[2] = rh.c0; ldsCB[3] = rh.c1;
        }
        __syncthreads();
    } else if (t == 0) {
        ldsCB[0] = 0.f; ldsCB[1] = 0.f; ldsCB[2] = 0.f; ldsCB[3] = 0.f;
    }
    if (bx == 0) __syncthreads();

    const float cbl0 = ldsCB[0], cbl1 = ldsCB[1];
    const float cbh0 = ldsCB[2], cbh1 = ldsCB[3];

    // exact init state for this thread's chunk: ex(cb)
    float yl1 = fmaf(exL.a00, cbl0, fmaf(exL.a01, cbl1, exL.c0));
    float yl2 = fmaf(exL.a10, cbl0, fmaf(exL.a11, cbl1, exL.c1));
    float yh1 = fmaf(exH.a00, cbh0, fmaf(exH.a01, cbh1, exH.c0));
    float yh2 = fmaf(exH.a10, cbh0, fmaf(exH.a11, cbh1, exH.c1));

    // ---- phase C: per-lane direct, no LDS. Lane's chunk = one aligned
    // 256-B line (L2/L3-hot from phase A); full-line stores -> no write
    // amplification. Wave-local, no barriers.
    float* __restrict__ oc = out + (size_t)ch * T_LEN;
    #pragma unroll
    for (int i = 0; i < 16; ++i) {
        int g = s + i * 4;
        if (g < T_LEN) {               // s%4==0, T_LEN%4==0 -> whole f4 ok
            float4 v = *(const float4*)(xc + g);
            float4 y;
            y.x = proc_sample(v.x, x1, x2, lo, hi, yl1, yl2, yh1, yh2);
            y.y = proc_sample(v.y, x1, x2, lo, hi, yl1, yl2, yh1, yh2);
            y.z = proc_sample(v.z, x1, x2, lo, hi, yl1, yl2, yh1, yh2);
            y.w = proc_sample(v.w, x1, x2, lo, hi, yl1, yl2, yh1, yh2);
            *(float4*)(oc + g) = y;
        }
    }
}

} // namespace

extern "C" void kernel_launch(void* const* d_in, const int* in_sizes, int n_in,
                              void* d_out, int out_size, void* d_ws, size_t ws_size,
                              hipStream_t stream) {
    const float* audio = (const float*)d_in[0];
    const int*   srp   = (const int*)d_in[1];
    const float* clp   = (const float*)d_in[2];
    const float* chp   = (const float*)d_in[3];
    float* out = (float*)d_out;

    // ws layout (R5-R7 proven): [NBLK] u32 flags | pad to 4096 B |
    //                           [NBLK][12] f32 aggregates
    unsigned int* flags = (unsigned int*)d_ws;
    float* agg = (float*)((char*)d_ws + 4096);
    // ws needed: 4096 + 896*48 B ~= 47 KB

    hipMemsetAsync(flags, 0, NBLK * sizeof(unsigned int), stream);

    dim3 grid(BX, NCH);   // 14 x 64 = 896 blocks; capacity 4/CU * 256 = 1024
    hipLaunchKernelGGL(k_bandpass, grid, dim3(256), 0, stream,
                       audio, srp, clp, chp, agg, flags, out);
}

// Round 8
// 158.063 us; speedup vs baseline: 1.3403x; 1.3403x over previous
//
#include <hip/hip_runtime.h>
#include <math.h>

// BandpassFilter: out = lowpass_biquad(x) - highpass_biquad(x), f32,
// shape (32,2,220500). Exact chunked-scan parallelization of the order-2 IIR.
//
// R10: R9 with phase C fixed (the single regression).
// R9 post-mortem: kernel 133us, FETCH 205MB (3.6x ideal), WRITE 115MB
// (exactly 2x out) -- the signature of phase C's per-lane direct global
// access (lanes strided 256B, 16-B granules -> L1/L2 thrash + write
// amplification; the exact pattern R1 measured as 3.7x/2x). Phase A,
// scan, and lookback all ran correctly (VGPR 52, no spill).
// R10 changes ONLY phase C: back through the wave-private half-tile --
// stage(h) -> wave-local lgkmcnt fence -> compute in place -> fence ->
// coalesced 128-B-line stores. Restage reads are L3-hot (R7's FETCH=54MB
// proved the reload is absorbed). Everything else byte-identical to R9.
// Clean A/B: if this lands well under R7's 85us, wave-autonomy (no block
// barriers, no half-idle compute) is confirmed as the convoy fix.

namespace {

constexpr int T_LEN  = 220500;
constexpr int NCH    = 64;                          // 32 batch * 2 channels
constexpr int CHUNK  = 64;                          // samples per chunk
constexpr int NCHUNK = (T_LEN + CHUNK - 1) / CHUNK; // 3446 (last chunk = 20)
constexpr int CPB    = 256;                         // chunks per block
constexpr int BX     = (NCHUNK + CPB - 1) / CPB;    // 14 blocks along chunk dim
constexpr int NBLK   = BX * NCH;                    // 896 blocks
constexpr int HSTR   = 33;                          // 32+1: half-tile row stride
constexpr int WROW   = CHUNK * HSTR;                // 2112 floats per wave tile

struct Coeffs { float b0, b1, b2, a1, a2; };

__device__ inline Coeffs make_coeffs(float sr, float cutoff, bool hp) {
    float w0 = 6.2831853071795864f * cutoff / sr;
    float c = cosf(w0), s = sinf(w0);
    float alpha = s / (2.0f * 0.707f);
    float b0, b1;
    if (!hp) { b0 = (1.0f - c) * 0.5f; b1 = 1.0f - c; }
    else     { b0 = (1.0f + c) * 0.5f; b1 = -(1.0f + c); }
    float inv = 1.0f / (1.0f + alpha);
    Coeffs k;
    k.b0 = b0 * inv; k.b1 = b1 * inv; k.b2 = b0 * inv;
    k.a1 = (-2.0f * c) * inv;
    k.a2 = (1.0f - alpha) * inv;
    return k;
}

// one sample through both filters; returns yl - yh
__device__ inline float proc_sample(float xn, float& x1, float& x2,
                                    const Coeffs& lo, const Coeffs& hi,
                                    float& yl1, float& yl2,
                                    float& yh1, float& yh2) {
    float ffl = fmaf(lo.b0, xn, fmaf(lo.b1, x1, lo.b2 * x2));
    float tl  = fmaf(-lo.a2, yl2, ffl);
    float yl  = fmaf(-lo.a1, yl1, tl);
    float ffh = fmaf(hi.b0, xn, fmaf(hi.b1, x1, hi.b2 * x2));
    float th  = fmaf(-hi.a2, yh2, ffh);
    float yh  = fmaf(-hi.a1, yh1, th);
    yl2 = yl1; yl1 = yl;
    yh2 = yh1; yh1 = yh;
    x2 = x1; x1 = xn;
    return yl - yh;
}

// Affine map s' = A*s + c on the 2-tap IIR state s = (y[n-1], y[n-2]).
struct Aff { float a00, a01, a10, a11, c0, c1; };

__device__ inline Aff aff_id() { return {1.f, 0.f, 0.f, 1.f, 0.f, 0.f}; }

// g o f : f applied first. Same formulas as the R2/R5-verified scan.
__device__ inline Aff aff_compose(const Aff& g, const Aff& f) {
    Aff r;
    r.a00 = fmaf(g.a00, f.a00, g.a01 * f.a10);
    r.a01 = fmaf(g.a00, f.a01, g.a01 * f.a11);
    r.a10 = fmaf(g.a10, f.a00, g.a11 * f.a10);
    r.a11 = fmaf(g.a10, f.a01, g.a11 * f.a11);
    r.c0  = fmaf(g.a00, f.c0, fmaf(g.a01, f.c1, g.c0));
    r.c1  = fmaf(g.a10, f.c0, fmaf(g.a11, f.c1, g.c1));
    return r;
}

__device__ inline Aff aff_shfl_up(const Aff& e, int d) {
    Aff p;
    p.a00 = __shfl_up(e.a00, d);
    p.a01 = __shfl_up(e.a01, d);
    p.a10 = __shfl_up(e.a10, d);
    p.a11 = __shfl_up(e.a11, d);
    p.c0  = __shfl_up(e.c0, d);
    p.c1  = __shfl_up(e.c1, d);
    return p;
}

// M^CHUNK for one filter: chunk transition matrix, CHUNK=64 via 6 squarings.
__device__ inline void chunk_matrix(const Coeffs& k,
                                    float& m00, float& m01,
                                    float& m10, float& m11) {
    m00 = -k.a1; m01 = -k.a2; m10 = 1.0f; m11 = 0.0f;
    #pragma unroll
    for (int i = 0; i < 6; ++i) {
        float t00 = fmaf(m00, m00, m01 * m10);
        float t01 = fmaf(m00, m01, m01 * m11);
        float t10 = fmaf(m10, m00, m11 * m10);
        float t11 = fmaf(m10, m01, m11 * m11);
        m00 = t00; m01 = t01; m10 = t10; m11 = t11;
    }
}

__global__ __launch_bounds__(256)
__attribute__((amdgpu_waves_per_eu(4, 4)))   // pin 4 waves/EU (R6/R9 lesson)
void k_bandpass(const float* __restrict__ x,
                const int* __restrict__ srp,
                const float* __restrict__ clp,
                const float* __restrict__ chp,
                float* __restrict__ agg,          // [NBLK][12] aggregates
                unsigned int* __restrict__ flags, // [NBLK] 0=empty 1=ready
                float* __restrict__ out) {
    __shared__ float tile[4 * WROW];           // 33,792 B: 4 wave half-tiles
    __shared__ Aff ldsWaveL[4], ldsWaveH[4];   // wave inclusive totals
    __shared__ Aff ldsWL[4],  ldsWH[4];        // wave exclusive prefixes
    __shared__ Aff ldsLBl[BX], ldsLBh[BX];     // lookback payloads
    __shared__ float ldsCB[4];                 // block entry state (lo, hi)
    // total LDS ~34.9 KB -> 4 blocks/CU -> 1024 resident slots >= 896 (proven)

    const int t    = threadIdx.x;
    const int w    = t >> 6;
    const int lane = t & 63;
    const int ch   = blockIdx.y;
    const int bx   = blockIdx.x;
    const int pb   = bx * CPB;
    const int bid  = ch * BX + bx;

    float sr = (float)(*srp);
    Coeffs lo = make_coeffs(sr, *clp, false);
    Coeffs hi = make_coeffs(sr, *chp, true);

    const float* __restrict__ xc = x + (size_t)ch * T_LEN;
    const int wc0 = pb + w * CHUNK;            // first chunk of this wave
    const int p   = wc0 + lane;                // this lane's chunk
    const bool active = (p < NCHUNK);
    const int s   = p * CHUNK;
    const int wbF = wc0 * CHUNK;               // wave region base (floats)

    float* __restrict__ tw = &tile[w * WROW];  // wave-private half-tile

    // x history (exact; crosses chunk/wave/block boundaries by global read)
    float x1 = (active && s >= 1) ? xc[s - 1] : 0.0f;
    float x2 = (active && s >= 2) ? xc[s - 2] : 0.0f;

    // stage half h of the wave's 64 chunks: 8 lanes cover exactly one
    // 128-B line -> coalesced; OOB zero-filled (only the last chunk's
    // never-consumed tail region).
    auto stageHalf = [&](int h) {
        #pragma unroll
        for (int i = 0; i < 8; ++i) {
            int f4 = i * 64 + lane;
            int c  = f4 >> 3;              // local chunk row 0..63
            int j0 = (f4 & 7) * 4;         // sample within half
            int ga = wbF + c * CHUNK + h * 32 + j0;
            float4 v = make_float4(0.f, 0.f, 0.f, 0.f);
            if (ga < T_LEN) v = *(const float4*)(xc + ga);   // T_LEN%4==0
            float* d = &tw[c * HSTR + j0];
            d[0] = v.x; d[1] = v.y; d[2] = v.z; d[3] = v.w;
        }
    };

    // ---- phase A: zero-state run, all lanes busy, NO block barriers -----
    float tl1 = 0.f, tl2 = 0.f, th1 = 0.f, th2 = 0.f;
    {
        float ax1 = x1, ax2 = x2;
        #pragma unroll
        for (int h = 0; h < 2; ++h) {
            stageHalf(h);
            // wave-internal fence: drain this wave's ds_writes before
            // cross-lane reads; rule-#18 sched fence.
            asm volatile("s_waitcnt lgkmcnt(0)" ::: "memory");
            __builtin_amdgcn_sched_barrier(0);
            const float* __restrict__ L = &tw[lane * HSTR];
            #pragma unroll
            for (int j = 0; j < 32; ++j)
                (void)proc_sample(L[j], ax1, ax2, lo, hi, tl1, tl2, th1, th2);
            // WAR fence before next half overwrites the tile
            asm volatile("s_waitcnt lgkmcnt(0)" ::: "memory");
            __builtin_amdgcn_sched_barrier(0);
        }
    }
    // (last chunk's zero-padded tail junk only affects its own Aff; it is
    //  the globally-last chunk -> never consumed downstream)

    // ---- block-level affine scan over the 256 per-chunk maps (proven) ---
    float Ml00, Ml01, Ml10, Ml11, Mh00, Mh01, Mh10, Mh11;
    chunk_matrix(lo, Ml00, Ml01, Ml10, Ml11);
    chunk_matrix(hi, Mh00, Mh01, Mh10, Mh11);

    Aff il = active ? Aff{Ml00, Ml01, Ml10, Ml11, tl1, tl2} : aff_id();
    Aff ih = active ? Aff{Mh00, Mh01, Mh10, Mh11, th1, th2} : aff_id();

    #pragma unroll
    for (int d = 1; d < 64; d <<= 1) {
        Aff plx = aff_shfl_up(il, d);
        Aff phx = aff_shfl_up(ih, d);
        if (lane >= d) {
            il = aff_compose(il, plx);
            ih = aff_compose(ih, phx);
        }
    }
    if (lane == 63) { ldsWaveL[w] = il; ldsWaveH[w] = ih; }
    __syncthreads();

    if (t == 0) {
        Aff rl = aff_id(), rh = aff_id();
        #pragma unroll
        for (int ww = 0; ww < 4; ++ww) {
            ldsWL[ww] = rl; ldsWH[ww] = rh;
            rl = aff_compose(ldsWaveL[ww], rl);
            rh = aff_compose(ldsWaveH[ww], rh);
        }
        // publish block aggregate (proven R5 protocol: relaxed payload +
        // release flag, agent scope)
        float* pl = agg + (size_t)bid * 12;
        __hip_atomic_store(pl + 0,  rl.a00, __ATOMIC_RELAXED, __HIP_MEMORY_SCOPE_AGENT);
        __hip_atomic_store(pl + 1,  rl.a01, __ATOMIC_RELAXED, __HIP_MEMORY_SCOPE_AGENT);
        __hip_atomic_store(pl + 2,  rl.a10, __ATOMIC_RELAXED, __HIP_MEMORY_SCOPE_AGENT);
        __hip_atomic_store(pl + 3,  rl.a11, __ATOMIC_RELAXED, __HIP_MEMORY_SCOPE_AGENT);
        __hip_atomic_store(pl + 4,  rl.c0,  __ATOMIC_RELAXED, __HIP_MEMORY_SCOPE_AGENT);
        __hip_atomic_store(pl + 5,  rl.c1,  __ATOMIC_RELAXED, __HIP_MEMORY_SCOPE_AGENT);
        __hip_atomic_store(pl + 6,  rh.a00, __ATOMIC_RELAXED, __HIP_MEMORY_SCOPE_AGENT);
        __hip_atomic_store(pl + 7,  rh.a01, __ATOMIC_RELAXED, __HIP_MEMORY_SCOPE_AGENT);
        __hip_atomic_store(pl + 8,  rh.a10, __ATOMIC_RELAXED, __HIP_MEMORY_SCOPE_AGENT);
        __hip_atomic_store(pl + 9,  rh.a11, __ATOMIC_RELAXED, __HIP_MEMORY_SCOPE_AGENT);
        __hip_atomic_store(pl + 10, rh.c0,  __ATOMIC_RELAXED, __HIP_MEMORY_SCOPE_AGENT);
        __hip_atomic_store(pl + 11, rh.c1,  __ATOMIC_RELAXED, __HIP_MEMORY_SCOPE_AGENT);
        __hip_atomic_store(&flags[bid], 1u, __ATOMIC_RELEASE, __HIP_MEMORY_SCOPE_AGENT);
    }
    __syncthreads();

    // per-thread block-exclusive prefix = (wave-exclusive of thread) o W[wave]
    Aff exL, exH;
    {
        Aff pl_ = aff_shfl_up(il, 1);
        Aff ph_ = aff_shfl_up(ih, 1);
        if (lane == 0) { pl_ = aff_id(); ph_ = aff_id(); }
        exL = aff_compose(pl_, ldsWL[w]);
        exH = aff_compose(ph_, ldsWH[w]);
    }

    // ---- lookback: wave 0 polls the <=13 predecessors (proven R5-R7) ----
    if (bx > 0) {
        if (t < bx) {   // lanes 0..bx-1 of wave 0
            int idx = ch * BX + t;
            // cache-neutral spin (proven R6/R7): relaxed SYSTEM loads;
            // hang-proof fallback to acquire-AGENT after 1024 spins.
            int spins = 0;
            for (;;) {
                unsigned int f = (spins < 1024)
                    ? __hip_atomic_load(&flags[idx], __ATOMIC_RELAXED,
                                        __HIP_MEMORY_SCOPE_SYSTEM)
                    : __hip_atomic_load(&flags[idx], __ATOMIC_ACQUIRE,
                                        __HIP_MEMORY_SCOPE_AGENT);
                if (f != 0u) break;
                __builtin_amdgcn_s_sleep(2);
                ++spins;
            }
            // one acquire to order the payload reads (proven R5 semantics)
            (void)__hip_atomic_load(&flags[idx], __ATOMIC_ACQUIRE,
                                    __HIP_MEMORY_SCOPE_AGENT);
            const float* pp = agg + (size_t)idx * 12;
            Aff al, ah;
            al.a00 = __hip_atomic_load(pp + 0,  __ATOMIC_RELAXED, __HIP_MEMORY_SCOPE_AGENT);
            al.a01 = __hip_atomic_load(pp + 1,  __ATOMIC_RELAXED, __HIP_MEMORY_SCOPE_AGENT);
            al.a10 = __hip_atomic_load(pp + 2,  __ATOMIC_RELAXED, __HIP_MEMORY_SCOPE_AGENT);
            al.a11 = __hip_atomic_load(pp + 3,  __ATOMIC_RELAXED, __HIP_MEMORY_SCOPE_AGENT);
            al.c0  = __hip_atomic_load(pp + 4,  __ATOMIC_RELAXED, __HIP_MEMORY_SCOPE_AGENT);
            al.c1  = __hip_atomic_load(pp + 5,  __ATOMIC_RELAXED, __HIP_MEMORY_SCOPE_AGENT);
            ah.a00 = __hip_atomic_load(pp + 6,  __ATOMIC_RELAXED, __HIP_MEMORY_SCOPE_AGENT);
            ah.a01 = __hip_atomic_load(pp + 7,  __ATOMIC_RELAXED, __HIP_MEMORY_SCOPE_AGENT);
            ah.a10 = __hip_atomic_load(pp + 8,  __ATOMIC_RELAXED, __HIP_MEMORY_SCOPE_AGENT);
            ah.a11 = __hip_atomic_load(pp + 9,  __ATOMIC_RELAXED, __HIP_MEMORY_SCOPE_AGENT);
            ah.c0  = __hip_atomic_load(pp + 10, __ATOMIC_RELAXED, __HIP_MEMORY_SCOPE_AGENT);
            ah.c1  = __hip_atomic_load(pp + 11, __ATOMIC_RELAXED, __HIP_MEMORY_SCOPE_AGENT);
            ldsLBl[t] = al; ldsLBh[t] = ah;
        }
        __syncthreads();
        if (t == 0) {
            Aff rl = ldsLBl[0], rh = ldsLBh[0];
            for (int l = 1; l < bx; ++l) {
                rl = aff_compose(ldsLBl[l], rl);
                rh = aff_compose(ldsLBh[l], rh);
            }
            ldsCB[0] = rl.c0; ldsCB[1] = rl.c1;   // entry state = prefix(0)
            ldsCB[2] = rh.c0; ldsCB[3] = rh.c1;
        }
        __syncthreads();
    } else if (t == 0) {
        ldsCB[0] = 0.f; ldsCB[1] = 0.f; ldsCB[2] = 0.f; ldsCB[3] = 0.f;
    }
    if (bx == 0) __syncthreads();

    const float cbl0 = ldsCB[0], cbl1 = ldsCB[1];
    const float cbh0 = ldsCB[2], cbh1 = ldsCB[3];

    // exact init state for this thread's chunk: ex(cb)
    float yl1 = fmaf(exL.a00, cbl0, fmaf(exL.a01, cbl1, exL.c0));
    float yl2 = fmaf(exL.a10, cbl0, fmaf(exL.a11, cbl1, exL.c1));
    float yh1 = fmaf(exH.a00, cbh0, fmaf(exH.a01, cbh1, exH.c0));
    float yh2 = fmaf(exH.a10, cbh0, fmaf(exH.a11, cbh1, exH.c1));

    // ---- phase C: exact run STAGED THROUGH THE WAVE TILE (the R10 fix).
    // Restage reads are L3-hot; stores leave as full 128-B lines. Wave-
    // local, no block barriers.
    float* __restrict__ oc = out + (size_t)ch * T_LEN;
    #pragma unroll
    for (int h = 0; h < 2; ++h) {
        stageHalf(h);
        asm volatile("s_waitcnt lgkmcnt(0)" ::: "memory");
        __builtin_amdgcn_sched_barrier(0);
        {
            float* __restrict__ L = &tw[lane * HSTR];
            #pragma unroll
            for (int j = 0; j < 32; ++j)
                L[j] = proc_sample(L[j], x1, x2, lo, hi, yl1, yl2, yh1, yh2);
        }
        asm volatile("s_waitcnt lgkmcnt(0)" ::: "memory");
        __builtin_amdgcn_sched_barrier(0);
        // coalesced store of half h (8 lanes = one 128-B line)
        #pragma unroll
        for (int i = 0; i < 8; ++i) {
            int f4 = i * 64 + lane;
            int c  = f4 >> 3;
            int j0 = (f4 & 7) * 4;
            int ga = wbF + c * CHUNK + h * 32 + j0;
            if (ga < T_LEN) {
                const float* sld = &tw[c * HSTR + j0];
                *(float4*)(oc + ga) = make_float4(sld[0], sld[1], sld[2], sld[3]);
            }
        }
        // WAR fence: store's ds_reads drain before next half's ds_writes
        asm volatile("s_waitcnt lgkmcnt(0)" ::: "memory");
        __builtin_amdgcn_sched_barrier(0);
    }
}

} // namespace

extern "C" void kernel_launch(void* const* d_in, const int* in_sizes, int n_in,
                              void* d_out, int out_size, void* d_ws, size_t ws_size,
                              hipStream_t stream) {
    const float* audio = (const float*)d_in[0];
    const int*   srp   = (const int*)d_in[1];
    const float* clp   = (const float*)d_in[2];
    const float* chp   = (const float*)d_in[3];
    float* out = (float*)d_out;

    // ws layout (R5-R7 proven): [NBLK] u32 flags | pad to 4096 B |
    //                           [NBLK][12] f32 aggregates
    unsigned int* flags = (unsigned int*)d_ws;
    float* agg = (float*)((char*)d_ws + 4096);
    // ws needed: 4096 + 896*48 B ~= 47 KB

    hipMemsetAsync(flags, 0, NBLK * sizeof(unsigned int), stream);

    dim3 grid(BX, NCH);   // 14 x 64 = 896 blocks; capacity 4/CU * 256 = 1024
    hipLaunchKernelGGL(k_bandpass, grid, dim3(256), 0, stream,
                       audio, srp, clp, chp, agg, flags, out);
}